// Round 2
// baseline (811.815 us; speedup 1.0000x reference)
//
#include <hip/hip_runtime.h>
#include <math.h>

#define H 64
#define IN_DIM 4800
#define DEPTH 14
#define NNODES ((1 << DEPTH) - 1)   // 16383

typedef __attribute__((ext_vector_type(8))) short short8;
typedef __attribute__((ext_vector_type(4))) float f32x4;

// ---------------- split W into bf16 hi/lo planes ----------------
// n4 = number of float4 chunks; one chunk per thread (grid sized exactly)
__global__ void convert_w(const float* __restrict__ W, ushort* __restrict__ Wh,
                          ushort* __restrict__ Wl, int n4)
{
    int i = blockIdx.x * blockDim.x + threadIdx.x;
    if (i >= n4) return;
    float4 v = *(const float4*)&W[i * 4];
    float xs[4] = {v.x, v.y, v.z, v.w};
    ushort hv[4], lv[4];
#pragma unroll
    for (int j = 0; j < 4; ++j) {
        unsigned xb = __float_as_uint(xs[j]);
        hv[j] = (ushort)(xb >> 16);
        float r = xs[j] - __uint_as_float(xb & 0xFFFF0000u);
        lv[j] = (ushort)(__float_as_uint(r) >> 16);
    }
    *(ushort4*)&Wh[i * 4] = make_ushort4(hv[0], hv[1], hv[2], hv[3]);
    *(ushort4*)&Wl[i * 4] = make_ushort4(lv[0], lv[1], lv[2], lv[3]);
}

// ---------------- GEMM: Wx = inputs @ Wx_w.T + Wx_b  (split-bf16 MFMA) ----
// A fp32 [NNODES][IN_DIM]; Bh/Bl bf16 [256][IN_DIM]; C fp32 [NNODES][256]
// C = Ah*Bh + Ah*Bl + Al*Bh  (Al*Bl term negligible)
#define BM 64
#define BN 128
#define BK 32
#define NT (IN_DIM / BK)   // 150

__global__ __launch_bounds__(256, 2) void gemm_split(
    const float* __restrict__ A,
    const ushort* __restrict__ Bh, const ushort* __restrict__ Bl,
    const float* __restrict__ bias, float* __restrict__ C)
{
    __shared__ ushort Ah_s[BM][BK];   // 4 KB
    __shared__ ushort Al_s[BM][BK];   // 4 KB
    __shared__ ushort Bh_s[BN][BK];   // 8 KB
    __shared__ ushort Bl_s[BN][BK];   // 8 KB

    const int tid  = threadIdx.x;
    const int wave = tid >> 6, lane = tid & 63;
    const int wm = wave >> 1, wn = wave & 1;       // 2x2 wave grid
    const int m0 = blockIdx.y * BM;
    const int n0 = blockIdx.x * BN;

    // A staging: 8 consecutive floats per thread: row=tid>>2, col=(tid&3)*8
    const int ar = tid >> 2, ac = (tid & 3) * 8;
    const int aRowC = (m0 + ar < NNODES) ? (m0 + ar) : (NNODES - 1);
    const float* aPtr = A + (size_t)aRowC * IN_DIM + ac;
    // B staging: 2 chunks of 8 bf16 per plane per thread
    const int br = tid >> 2, bc = (tid & 3) * 8;
    const ushort* bhPtr = Bh + (size_t)(n0 + br) * IN_DIM + bc;
    const ushort* blPtr = Bl + (size_t)(n0 + br) * IN_DIM + bc;

    f32x4 acc[2][4] = {};

    float4 a_reg0, a_reg1;
    short8 bh_reg0, bh_reg1, bl_reg0, bl_reg1;

#define LOAD_TILE(t)                                                          \
    {                                                                         \
        const int k0 = (t) * BK;                                              \
        a_reg0 = *(const float4*)(aPtr + k0);                                 \
        a_reg1 = *(const float4*)(aPtr + k0 + 4);                             \
        bh_reg0 = *(const short8*)(bhPtr + k0);                               \
        bh_reg1 = *(const short8*)(bhPtr + (size_t)64 * IN_DIM + k0);         \
        bl_reg0 = *(const short8*)(blPtr + k0);                               \
        bl_reg1 = *(const short8*)(blPtr + (size_t)64 * IN_DIM + k0);         \
    }

#define WRITE_TILE()                                                          \
    {                                                                         \
        float xs[8] = {a_reg0.x, a_reg0.y, a_reg0.z, a_reg0.w,                \
                       a_reg1.x, a_reg1.y, a_reg1.z, a_reg1.w};               \
        short8 hv, lv;                                                        \
        _Pragma("unroll")                                                     \
        for (int j = 0; j < 8; ++j) {                                         \
            unsigned xb = __float_as_uint(xs[j]);                             \
            hv[j] = (short)(xb >> 16);                                        \
            float r = xs[j] - __uint_as_float(xb & 0xFFFF0000u);              \
            lv[j] = (short)(__float_as_uint(r) >> 16);                        \
        }                                                                     \
        *(short8*)&Ah_s[ar][ac] = hv;                                         \
        *(short8*)&Al_s[ar][ac] = lv;                                         \
        *(short8*)&Bh_s[br][bc] = bh_reg0;                                    \
        *(short8*)&Bh_s[64 + br][bc] = bh_reg1;                               \
        *(short8*)&Bl_s[br][bc] = bl_reg0;                                    \
        *(short8*)&Bl_s[64 + br][bc] = bl_reg1;                               \
    }

    LOAD_TILE(0);
    WRITE_TILE();
    __syncthreads();

    const int fr = lane & 15, kg = (lane >> 4) * 8;

    for (int t = 0; t < NT; ++t) {
        if (t + 1 < NT) LOAD_TILE(t + 1);   // prefetch next tile into regs

        short8 ah[2], al[2], bh[4], bl[4];
#pragma unroll
        for (int mf = 0; mf < 2; ++mf) {
            int r = wm * 32 + mf * 16 + fr;
            ah[mf] = *(const short8*)&Ah_s[r][kg];
            al[mf] = *(const short8*)&Al_s[r][kg];
        }
#pragma unroll
        for (int nf = 0; nf < 4; ++nf) {
            int r = wn * 64 + nf * 16 + fr;
            bh[nf] = *(const short8*)&Bh_s[r][kg];
            bl[nf] = *(const short8*)&Bl_s[r][kg];
        }
#pragma unroll
        for (int mf = 0; mf < 2; ++mf)
#pragma unroll
            for (int nf = 0; nf < 4; ++nf) {
                acc[mf][nf] = __builtin_amdgcn_mfma_f32_16x16x32_bf16(ah[mf], bh[nf], acc[mf][nf], 0, 0, 0);
                acc[mf][nf] = __builtin_amdgcn_mfma_f32_16x16x32_bf16(ah[mf], bl[nf], acc[mf][nf], 0, 0, 0);
                acc[mf][nf] = __builtin_amdgcn_mfma_f32_16x16x32_bf16(al[mf], bh[nf], acc[mf][nf], 0, 0, 0);
            }
        __syncthreads();
        if (t + 1 < NT) { WRITE_TILE(); __syncthreads(); }
    }

    // epilogue: C/D layout col = lane&15, row = (lane>>4)*4 + reg
    const int rquad = (lane >> 4) * 4;
#pragma unroll
    for (int nf = 0; nf < 4; ++nf) {
        int n = n0 + wn * 64 + nf * 16 + fr;
        float bv = bias[n];
#pragma unroll
        for (int mf = 0; mf < 2; ++mf) {
            int mbase = m0 + wm * 32 + mf * 16 + rquad;
#pragma unroll
            for (int j = 0; j < 4; ++j) {
                int m = mbase + j;
                if (m < NNODES)
                    C[(size_t)m * 256 + n] = acc[mf][nf][j] + bv;
            }
        }
    }
#undef LOAD_TILE
#undef WRITE_TILE
}

// ---------------- Tree level kernel (unchanged from round 0) ----------------
__device__ __forceinline__ float sigmoidf_(float x) { return 1.0f / (1.0f + expf(-x)); }

__global__ __launch_bounds__(256) void level_kernel(
    const float* __restrict__ Wx,
    const float* __restrict__ convW,   // [64][2][64]
    const float* __restrict__ conv_b,  // [64]
    const float* __restrict__ Ui, const float* __restrict__ Uf,
    const float* __restrict__ Uo, const float* __restrict__ Uu,  // [64][64]
    float* __restrict__ harr, float* __restrict__ carr,
    int base, int n, int isLeaf)
{
    __shared__ float sh[4][192];  // per wave: hl[64] | hr[64] | avg[64]
    const int wave = threadIdx.x >> 6;
    const int lane = threadIdx.x & 63;
    const int node = blockIdx.x * 4 + wave;
    const bool active = node < n;
    const int idx = base + node;

    float xi = 0.f, xf = 0.f, xo = 0.f, xu = 0.f;
    float avg = 0.f, sumf = 0.f, cl = 0.f, cr = 0.f;

    if (active) {
        xi = Wx[idx * 256 + lane];
        xf = Wx[idx * 256 + 64 + lane];
        xo = Wx[idx * 256 + 128 + lane];
        xu = Wx[idx * 256 + 192 + lane];
        avg = conv_b[lane];
        if (!isLeaf) {
            int li = 2 * idx + 1, ri = 2 * idx + 2;
            float hl = harr[li * 64 + lane];
            float hr = harr[ri * 64 + lane];
            cl = carr[li * 64 + lane];
            cr = carr[ri * 64 + lane];
            sh[wave][lane] = hl;
            sh[wave][64 + lane] = hr;
        }
    }
    __syncthreads();

    if (active && !isLeaf) {
        float fa_l = 0.f, fa_r = 0.f;
#pragma unroll
        for (int t4 = 0; t4 < 16; ++t4) {
            float4 vl = *(const float4*)&sh[wave][t4 * 4];
            float4 vr = *(const float4*)&sh[wave][64 + t4 * 4];
            float4 w0 = *(const float4*)&convW[lane * 128 + t4 * 4];
            float4 w1 = *(const float4*)&convW[lane * 128 + 64 + t4 * 4];
            float4 uf = *(const float4*)&Uf[lane * 64 + t4 * 4];
            avg += w0.x * vl.x + w0.y * vl.y + w0.z * vl.z + w0.w * vl.w;
            avg += w1.x * vr.x + w1.y * vr.y + w1.z * vr.z + w1.w * vr.w;
            fa_l += uf.x * vl.x + uf.y * vl.y + uf.z * vl.z + uf.w * vl.w;
            fa_r += uf.x * vr.x + uf.y * vr.y + uf.z * vr.z + uf.w * vr.w;
        }
        float fl = sigmoidf_(xf + fa_l);
        float fr = sigmoidf_(xf + fa_r);
        sumf = fl * cl + fr * cr;
    }

    if (active) sh[wave][128 + lane] = avg;
    __syncthreads();

    if (active) {
        float ai = 0.f, ao = 0.f, au = 0.f;
#pragma unroll
        for (int t4 = 0; t4 < 16; ++t4) {
            float4 v  = *(const float4*)&sh[wave][128 + t4 * 4];
            float4 wi = *(const float4*)&Ui[lane * 64 + t4 * 4];
            float4 wo = *(const float4*)&Uo[lane * 64 + t4 * 4];
            float4 wu = *(const float4*)&Uu[lane * 64 + t4 * 4];
            ai += wi.x * v.x + wi.y * v.y + wi.z * v.z + wi.w * v.w;
            ao += wo.x * v.x + wo.y * v.y + wo.z * v.z + wo.w * v.w;
            au += wu.x * v.x + wu.y * v.y + wu.z * v.z + wu.w * v.w;
        }
        float iv = sigmoidf_(xi + ai);
        float ov = sigmoidf_(xo + ao);
        float uv = tanhf(xu + au);
        float cv = sumf + iv * uv;
        float hv = ov * tanhf(cv);
        harr[idx * 64 + lane] = hv;
        carr[idx * 64 + lane] = cv;
    }
}

// ---------------- Output: d_out = [h_root(64) | c_root(64)] ----------------
__global__ void out_kernel(const float* __restrict__ h, const float* __restrict__ c,
                           float* __restrict__ out)
{
    int t = threadIdx.x;
    if (t < 64) out[t] = h[t];
    else out[t] = c[t - 64];
}

extern "C" void kernel_launch(void* const* d_in, const int* in_sizes, int n_in,
                              void* d_out, int out_size, void* d_ws, size_t ws_size,
                              hipStream_t stream)
{
    const float* inputs = (const float*)d_in[0];
    const float* Wx_w   = (const float*)d_in[1];
    const float* Wx_b   = (const float*)d_in[2];
    const float* Ui     = (const float*)d_in[3];
    const float* Uf     = (const float*)d_in[4];
    const float* Uo     = (const float*)d_in[5];
    const float* Uu     = (const float*)d_in[6];
    const float* convW  = (const float*)d_in[7];
    const float* conv_b = (const float*)d_in[8];

    // workspace layout
    float*  Wx = (float*)d_ws;                                    // 16.8 MB
    float*  h  = (float*)((char*)d_ws + (size_t)(20u << 20));     // 4.2 MB
    float*  c  = (float*)((char*)d_ws + (size_t)(25u << 20));     // 4.2 MB
    ushort* Wh = (ushort*)((char*)d_ws + (size_t)(30u << 20));    // 2.4 MB
    ushort* Wl = (ushort*)((char*)d_ws + (size_t)(33u << 20));    // 2.4 MB

    // 1. split W into bf16 hi/lo planes (256*4800 = 1,228,800 elems = 307,200 float4)
    convert_w<<<1200, 256, 0, stream>>>(Wx_w, Wh, Wl, 307200);

    // 2. input projection GEMM on matrix cores
    dim3 ggrid(2, 256);   // (N-tiles of 128, M-tiles of 64)
    gemm_split<<<ggrid, 256, 0, stream>>>(inputs, Wh, Wl, Wx_b, Wx);

    // 3. bottom-up tree sweep
    for (int d = DEPTH - 1; d >= 0; --d) {
        int n = 1 << d;
        int base = n - 1;
        int blocks = (n + 3) >> 2;   // 4 nodes (waves) per block
        level_kernel<<<blocks, 256, 0, stream>>>(Wx, convW, conv_b, Ui, Uf, Uo, Uu,
                                                 h, c, base, n, (d == DEPTH - 1) ? 1 : 0);
    }

    out_kernel<<<1, 128, 0, stream>>>(h, c, (float*)d_out);
}